// Round 1
// baseline (502.780 us; speedup 1.0000x reference)
//
#include <hip/hip_runtime.h>

// GCN 2-layer forward on MI355X.
// Pipeline: deg count -> dinv -> GEMM1(+selfloop seed) -> edge-scatter(atomic)
//           -> GEMM2(fused leaky_relu+b1 on load, +b2 seed on store) -> edge-scatter.

__global__ void k_deg(const int* __restrict__ dst, int* __restrict__ deg, int E) {
    int i = blockIdx.x * blockDim.x + threadIdx.x;
    if (i < E) atomicAdd(&deg[dst[i]], 1);
}

__global__ void k_dinv(const int* __restrict__ deg, float* __restrict__ dinv, int n) {
    int i = blockIdx.x * blockDim.x + threadIdx.x;
    if (i < n) dinv[i] = rsqrtf((float)(deg[i] + 1));  // +1 = self-loop
}

// h = x @ W1  (x: n x 128, W1: 128 x 64), seed = h * dinv^2 (self-loop term)
__global__ __launch_bounds__(256) void k_gemm1(
    const float* __restrict__ x, const float* __restrict__ W,
    const float* __restrict__ dinv,
    float* __restrict__ h, float* __restrict__ seed, int n) {
    __shared__ float Wl[128 * 64];
    for (int i = threadIdx.x; i < 128 * 64; i += 256) Wl[i] = W[i];
    __syncthreads();
    const int lane = threadIdx.x & 63;
    const int wid  = blockIdx.x * 4 + (threadIdx.x >> 6);
    const int nw   = gridDim.x * 4;
    for (int r = wid; r < n; r += nw) {
        float xv0 = x[r * 128 + lane];
        float xv1 = x[r * 128 + 64 + lane];
        float acc0 = 0.f, acc1 = 0.f;
#pragma unroll
        for (int k = 0; k < 64; k += 2) {
            acc0 += __shfl(xv0, k)     * Wl[k * 64 + lane];
            acc1 += __shfl(xv0, k + 1) * Wl[(k + 1) * 64 + lane];
        }
#pragma unroll
        for (int k = 0; k < 64; k += 2) {
            acc0 += __shfl(xv1, k)     * Wl[(64 + k) * 64 + lane];
            acc1 += __shfl(xv1, k + 1) * Wl[(64 + k + 1) * 64 + lane];
        }
        float acc = acc0 + acc1;
        float di = dinv[r];
        h[r * 64 + lane] = acc;
        seed[r * 64 + lane] = acc * di * di;
    }
}

// h2 = leaky_relu(pre + b1) @ W2 ; seed(out) = h2 * dinv^2 + b2
__global__ __launch_bounds__(256) void k_gemm2(
    const float* __restrict__ pre, const float* __restrict__ b1,
    const float* __restrict__ W, const float* __restrict__ b2,
    const float* __restrict__ dinv,
    float* __restrict__ h2, float* __restrict__ seed, int n) {
    __shared__ float Wl[64 * 64];
    for (int i = threadIdx.x; i < 64 * 64; i += 256) Wl[i] = W[i];
    __syncthreads();
    const int lane = threadIdx.x & 63;
    const float b1l = b1[lane];
    const float b2l = b2[lane];
    const int wid = blockIdx.x * 4 + (threadIdx.x >> 6);
    const int nw  = gridDim.x * 4;
    for (int r = wid; r < n; r += nw) {
        float v = pre[r * 64 + lane] + b1l;
        float a = v > 0.f ? v : 0.01f * v;   // leaky_relu(0.01)
        float acc0 = 0.f, acc1 = 0.f;
#pragma unroll
        for (int k = 0; k < 64; k += 2) {
            acc0 += __shfl(a, k)     * Wl[k * 64 + lane];
            acc1 += __shfl(a, k + 1) * Wl[(k + 1) * 64 + lane];
        }
        float acc = acc0 + acc1;
        float di = dinv[r];
        h2[r * 64 + lane] = acc;
        seed[r * 64 + lane] = acc * di * di + b2l;
    }
}

// out[dst] += h[src] * dinv[src] * dinv[dst], thread = (edge, col)
__global__ void k_agg(const int* __restrict__ src, const int* __restrict__ dst,
                      const float* __restrict__ dinv, const float* __restrict__ h,
                      float* __restrict__ out, int E) {
    const int total = E * 64;
    const int stride = gridDim.x * blockDim.x;
    for (int idx = blockIdx.x * blockDim.x + threadIdx.x; idx < total; idx += stride) {
        int e = idx >> 6;
        int c = idx & 63;
        int s = src[e], d = dst[e];
        float m = h[s * 64 + c] * dinv[s] * dinv[d];
        unsafeAtomicAdd(&out[d * 64 + c], m);
    }
}

extern "C" void kernel_launch(void* const* d_in, const int* in_sizes, int n_in,
                              void* d_out, int out_size, void* d_ws, size_t ws_size,
                              hipStream_t stream) {
    const float* x  = (const float*)d_in[0];
    const int*   ei = (const int*)d_in[1];
    const float* W1 = (const float*)d_in[2];
    const float* b1 = (const float*)d_in[3];
    const float* W2 = (const float*)d_in[4];
    const float* b2 = (const float*)d_in[5];
    float* out = (float*)d_out;

    const int n = in_sizes[0] / 128;   // 50000
    const int E = in_sizes[1] / 2;     // 800000
    const int* src = ei;
    const int* dst = ei + E;

    // workspace layout (h1 and h2 alias; h1 dead after first k_agg)
    char* ws = (char*)d_ws;
    size_t off = 0;
    int* deg = (int*)(ws + off);           off += ((size_t)n * 4 + 255) & ~(size_t)255;
    float* dinv = (float*)(ws + off);      off += ((size_t)n * 4 + 255) & ~(size_t)255;
    float* h = (float*)(ws + off);         off += ((size_t)n * 64 * 4 + 255) & ~(size_t)255;
    float* out1 = (float*)(ws + off);      off += ((size_t)n * 64 * 4 + 255) & ~(size_t)255;
    (void)ws_size; (void)n_in; (void)out_size;

    hipMemsetAsync(deg, 0, (size_t)n * 4, stream);
    k_deg <<<(E + 255) / 256, 256, 0, stream>>>(dst, deg, E);
    k_dinv<<<(n + 255) / 256, 256, 0, stream>>>(deg, dinv, n);

    k_gemm1<<<1024, 256, 0, stream>>>(x, W1, dinv, h, out1, n);
    k_agg  <<<2048, 256, 0, stream>>>(src, dst, dinv, h, out1, E);

    k_gemm2<<<1024, 256, 0, stream>>>(out1, b1, W2, b2, dinv, h, out, n);
    k_agg  <<<2048, 256, 0, stream>>>(src, dst, dinv, h, out, E);
}

// Round 2
// 422.770 us; speedup vs baseline: 1.1893x; 1.1893x over previous
//
#include <hip/hip_runtime.h>

// GCN 2-layer forward, CSR-by-dst aggregation (no f32 atomics).
// deg -> dinv -> scan(rowptr,cursor) -> scatter csr(src,w) -> GEMM1 ->
// agg1(+self,+b1) -> GEMM2(leaky on load) -> agg2(+self,+b2) -> d_out

__global__ void k_deg(const int* __restrict__ dst, int* __restrict__ deg, int E) {
    int i = blockIdx.x * blockDim.x + threadIdx.x;
    if (i < E) atomicAdd(&deg[dst[i]], 1);
}

__global__ void k_dinv(const int* __restrict__ deg, float* __restrict__ dinv, int n) {
    int i = blockIdx.x * blockDim.x + threadIdx.x;
    if (i < n) dinv[i] = rsqrtf((float)(deg[i] + 1));  // +1 = self-loop
}

// single-block exclusive scan: deg -> rowptr[0..n], duplicate into cursor
__global__ __launch_bounds__(1024) void k_scan(const int* __restrict__ deg,
                                               int* __restrict__ rowptr,
                                               int* __restrict__ cursor, int n) {
    __shared__ int psum[1024];
    const int t = threadIdx.x;
    const int chunk = (n + 1023) / 1024;
    const int beg = t * chunk;
    const int end = min(beg + chunk, n);
    int s = 0;
    for (int i = beg; i < end; ++i) s += deg[i];
    psum[t] = s;
    __syncthreads();
    if (t == 0) {
        int run = 0;
        for (int i = 0; i < 1024; ++i) { int v = psum[i]; psum[i] = run; run += v; }
    }
    __syncthreads();
    int run = psum[t];
    for (int i = beg; i < end; ++i) { rowptr[i] = run; cursor[i] = run; run += deg[i]; }
    if (beg < n && end == n) rowptr[n] = run;   // == E
}

// scatter edge records grouped by dst: csr[pos] = (src, dinv[src])
__global__ void k_scatter(const int* __restrict__ src, const int* __restrict__ dst,
                          const float* __restrict__ dinv, int* __restrict__ cursor,
                          float2* __restrict__ csr, int E) {
    int e = blockIdx.x * blockDim.x + threadIdx.x;
    if (e < E) {
        int s = src[e], d = dst[e];
        int pos = atomicAdd(&cursor[d], 1);
        csr[pos] = make_float2(__int_as_float(s), dinv[s]);
    }
}

// h = x @ W1  (x: n x 128, W1: 128 x 64)
__global__ __launch_bounds__(256) void k_gemm1(
    const float* __restrict__ x, const float* __restrict__ W,
    float* __restrict__ h, int n) {
    __shared__ float Wl[128 * 64];
    for (int i = threadIdx.x; i < 128 * 64; i += 256) Wl[i] = W[i];
    __syncthreads();
    const int lane = threadIdx.x & 63;
    const int wid  = blockIdx.x * 4 + (threadIdx.x >> 6);
    const int nw   = gridDim.x * 4;
    for (int r = wid; r < n; r += nw) {
        float xv0 = x[r * 128 + lane];
        float xv1 = x[r * 128 + 64 + lane];
        float acc0 = 0.f, acc1 = 0.f;
#pragma unroll
        for (int k = 0; k < 64; k += 2) {
            acc0 += __shfl(xv0, k)     * Wl[k * 64 + lane];
            acc1 += __shfl(xv0, k + 1) * Wl[(k + 1) * 64 + lane];
        }
#pragma unroll
        for (int k = 0; k < 64; k += 2) {
            acc0 += __shfl(xv1, k)     * Wl[(64 + k) * 64 + lane];
            acc1 += __shfl(xv1, k + 1) * Wl[(64 + k + 1) * 64 + lane];
        }
        h[r * 64 + lane] = acc0 + acc1;
    }
}

// h2 = leaky_relu(pre) @ W2   (b1 already folded into agg1 output)
__global__ __launch_bounds__(256) void k_gemm2(
    const float* __restrict__ pre, const float* __restrict__ W,
    float* __restrict__ h2, int n) {
    __shared__ float Wl[64 * 64];
    for (int i = threadIdx.x; i < 64 * 64; i += 256) Wl[i] = W[i];
    __syncthreads();
    const int lane = threadIdx.x & 63;
    const int wid = blockIdx.x * 4 + (threadIdx.x >> 6);
    const int nw  = gridDim.x * 4;
    for (int r = wid; r < n; r += nw) {
        float v = pre[r * 64 + lane];
        float a = v > 0.f ? v : 0.01f * v;   // leaky_relu(0.01)
        float acc0 = 0.f, acc1 = 0.f;
#pragma unroll
        for (int k = 0; k < 64; k += 2) {
            acc0 += __shfl(a, k)     * Wl[k * 64 + lane];
            acc1 += __shfl(a, k + 1) * Wl[(k + 1) * 64 + lane];
        }
        h2[r * 64 + lane] = acc0 + acc1;
    }
}

// out[d] = dinv[d] * sum_e w_e * h[s_e] + dinv[d]^2 * h[d] + bias
// one wave per dst node; lane = output column
__global__ __launch_bounds__(256) void k_aggcsr(
    const int* __restrict__ rowptr, const float2* __restrict__ csr,
    const float* __restrict__ dinv, const float* __restrict__ h,
    const float* __restrict__ bias, float* __restrict__ out, int n) {
    const int lane = threadIdx.x & 63;
    const int wid  = blockIdx.x * 4 + (threadIdx.x >> 6);
    const int nw   = gridDim.x * 4;
    const float bl = bias ? bias[lane] : 0.f;
    for (int d = wid; d < n; d += nw) {
        const int beg = rowptr[d], end = rowptr[d + 1];
        float acc = 0.f;
        for (int base = beg; base < end; base += 64) {
            const int m = min(64, end - base);
            float2 rec = (lane < m) ? csr[base + lane] : make_float2(0.f, 0.f);
            int   sv = __float_as_int(rec.x);
            for (int j = 0; j < m; ++j) {
                int   s = __shfl(sv, j);
                float w = __shfl(rec.y, j);
                acc += w * h[s * 64 + lane];
            }
        }
        const float di = dinv[d];
        out[d * 64 + lane] = acc * di + h[d * 64 + lane] * di * di + bl;
    }
}

extern "C" void kernel_launch(void* const* d_in, const int* in_sizes, int n_in,
                              void* d_out, int out_size, void* d_ws, size_t ws_size,
                              hipStream_t stream) {
    const float* x  = (const float*)d_in[0];
    const int*   ei = (const int*)d_in[1];
    const float* W1 = (const float*)d_in[2];
    const float* b1 = (const float*)d_in[3];
    const float* W2 = (const float*)d_in[4];
    const float* b2 = (const float*)d_in[5];
    float* out = (float*)d_out;

    const int n = in_sizes[0] / 128;   // 50000
    const int E = in_sizes[1] / 2;     // 800000
    const int* src = ei;
    const int* dst = ei + E;

    char* ws = (char*)d_ws;
    size_t off = 0;
    auto alloc = [&](size_t bytes) { void* p = ws + off; off = (off + bytes + 255) & ~(size_t)255; return p; };
    int*    deg    = (int*)alloc((size_t)n * 4);
    float*  dinv   = (float*)alloc((size_t)n * 4);
    int*    rowptr = (int*)alloc((size_t)(n + 1) * 4);
    int*    cursor = (int*)alloc((size_t)n * 4);
    float2* csr    = (float2*)alloc((size_t)E * 8);
    float*  h      = (float*)alloc((size_t)n * 64 * 4);
    float*  out1   = (float*)alloc((size_t)n * 64 * 4);
    (void)ws_size; (void)n_in; (void)out_size;

    hipMemsetAsync(deg, 0, (size_t)n * 4, stream);
    k_deg    <<<(E + 255) / 256, 256, 0, stream>>>(dst, deg, E);
    k_dinv   <<<(n + 255) / 256, 256, 0, stream>>>(deg, dinv, n);
    k_scan   <<<1, 1024, 0, stream>>>(deg, rowptr, cursor, n);
    k_scatter<<<(E + 255) / 256, 256, 0, stream>>>(src, dst, dinv, cursor, csr, E);

    k_gemm1 <<<1024, 256, 0, stream>>>(x, W1, h, n);
    k_aggcsr<<<2048, 256, 0, stream>>>(rowptr, csr, dinv, h, b1, out1, n);

    k_gemm2 <<<1024, 256, 0, stream>>>(out1, W2, h, n);
    k_aggcsr<<<2048, 256, 0, stream>>>(rowptr, csr, dinv, h, b2, out, n);
}

// Round 3
// 319.162 us; speedup vs baseline: 1.5753x; 1.3246x over previous
//
#include <hip/hip_runtime.h>

// GCN 2-layer forward, CSR-by-dst aggregation (no f32 atomics).
// deg -> dinv -> hierarchical scan (bsum/sbsum/scanfinal) -> scatter csr(src,w)
// -> GEMM1 -> agg1(+self,+b1) -> GEMM2(leaky on load) -> agg2(+self,+b2)

__global__ void k_deg(const int* __restrict__ dst, int* __restrict__ deg, int E) {
    int i = blockIdx.x * blockDim.x + threadIdx.x;
    if (i < E) atomicAdd(&deg[dst[i]], 1);
}

__global__ void k_dinv(const int* __restrict__ deg, float* __restrict__ dinv, int n) {
    int i = blockIdx.x * blockDim.x + threadIdx.x;
    if (i < n) dinv[i] = rsqrtf((float)(deg[i] + 1));  // +1 = self-loop
}

// per-block (1024-elem) sum of deg -> bsum[block]
__global__ __launch_bounds__(1024) void k_bsum(const int* __restrict__ deg,
                                               int* __restrict__ bsum, int n) {
    __shared__ int red[16];
    const int t = threadIdx.x;
    const int i = blockIdx.x * 1024 + t;
    int v = (i < n) ? deg[i] : 0;
#pragma unroll
    for (int o = 32; o; o >>= 1) v += __shfl_down(v, o);
    if ((t & 63) == 0) red[t >> 6] = v;
    __syncthreads();
    if (t == 0) {
        int s = 0;
#pragma unroll
        for (int w = 0; w < 16; ++w) s += red[w];
        bsum[blockIdx.x] = s;
    }
}

// exclusive scan of nb block sums (nb ~ 49) -> boff
__global__ void k_sbsum(const int* __restrict__ bsum, int* __restrict__ boff, int nb) {
    if (threadIdx.x == 0 && blockIdx.x == 0) {
        int run = 0;
        for (int i = 0; i < nb; ++i) { boff[i] = run; run += bsum[i]; }
    }
}

// per-block Hillis-Steele scan + block offset -> rowptr, cursor; rowptr[n]=E
__global__ __launch_bounds__(1024) void k_scanfinal(
    const int* __restrict__ deg, const int* __restrict__ boff,
    int* __restrict__ rowptr, int* __restrict__ cursor, int n) {
    __shared__ int sh[1024];
    const int t = threadIdx.x;
    const int i = blockIdx.x * 1024 + t;
    const int v = (i < n) ? deg[i] : 0;
    sh[t] = v;
    __syncthreads();
#pragma unroll
    for (int o = 1; o < 1024; o <<= 1) {
        int add = (t >= o) ? sh[t - o] : 0;
        __syncthreads();
        sh[t] += add;
        __syncthreads();
    }
    const int base = boff[blockIdx.x];
    const int excl = base + sh[t] - v;
    if (i < n) { rowptr[i] = excl; cursor[i] = excl; }
    if (i == n - 1) rowptr[n] = excl + v;   // == E
}

// scatter edge records grouped by dst: csr[pos] = (src, dinv[src])
__global__ void k_scatter(const int* __restrict__ src, const int* __restrict__ dst,
                          const float* __restrict__ dinv, int* __restrict__ cursor,
                          float2* __restrict__ csr, int E) {
    int e = blockIdx.x * blockDim.x + threadIdx.x;
    if (e < E) {
        int s = src[e], d = dst[e];
        int pos = atomicAdd(&cursor[d], 1);
        csr[pos] = make_float2(__int_as_float(s), dinv[s]);
    }
}

// h = x @ W1  (x: n x 128, W1: 128 x 64)
__global__ __launch_bounds__(256) void k_gemm1(
    const float* __restrict__ x, const float* __restrict__ W,
    float* __restrict__ h, int n) {
    __shared__ float Wl[128 * 64];
    for (int i = threadIdx.x; i < 128 * 64; i += 256) Wl[i] = W[i];
    __syncthreads();
    const int lane = threadIdx.x & 63;
    const int wid  = blockIdx.x * 4 + (threadIdx.x >> 6);
    const int nw   = gridDim.x * 4;
    for (int r = wid; r < n; r += nw) {
        float xv0 = x[r * 128 + lane];
        float xv1 = x[r * 128 + 64 + lane];
        float acc0 = 0.f, acc1 = 0.f;
#pragma unroll
        for (int k = 0; k < 64; k += 2) {
            acc0 += __shfl(xv0, k)     * Wl[k * 64 + lane];
            acc1 += __shfl(xv0, k + 1) * Wl[(k + 1) * 64 + lane];
        }
#pragma unroll
        for (int k = 0; k < 64; k += 2) {
            acc0 += __shfl(xv1, k)     * Wl[(64 + k) * 64 + lane];
            acc1 += __shfl(xv1, k + 1) * Wl[(64 + k + 1) * 64 + lane];
        }
        h[r * 64 + lane] = acc0 + acc1;
    }
}

// h2 = leaky_relu(pre) @ W2   (b1 already folded into agg1 output)
__global__ __launch_bounds__(256) void k_gemm2(
    const float* __restrict__ pre, const float* __restrict__ W,
    float* __restrict__ h2, int n) {
    __shared__ float Wl[64 * 64];
    for (int i = threadIdx.x; i < 64 * 64; i += 256) Wl[i] = W[i];
    __syncthreads();
    const int lane = threadIdx.x & 63;
    const int wid = blockIdx.x * 4 + (threadIdx.x >> 6);
    const int nw  = gridDim.x * 4;
    for (int r = wid; r < n; r += nw) {
        float v = pre[r * 64 + lane];
        float a = v > 0.f ? v : 0.01f * v;   // leaky_relu(0.01)
        float acc0 = 0.f, acc1 = 0.f;
#pragma unroll
        for (int k = 0; k < 64; k += 2) {
            acc0 += __shfl(a, k)     * Wl[k * 64 + lane];
            acc1 += __shfl(a, k + 1) * Wl[(k + 1) * 64 + lane];
        }
        h2[r * 64 + lane] = acc0 + acc1;
    }
}

// out[d] = dinv[d] * sum_e w_e * h[s_e] + dinv[d]^2 * h[d] + bias
// one wave per dst node; lane = output column
__global__ __launch_bounds__(256) void k_aggcsr(
    const int* __restrict__ rowptr, const float2* __restrict__ csr,
    const float* __restrict__ dinv, const float* __restrict__ h,
    const float* __restrict__ bias, float* __restrict__ out, int n) {
    const int lane = threadIdx.x & 63;
    const int wid  = blockIdx.x * 4 + (threadIdx.x >> 6);
    const int nw   = gridDim.x * 4;
    const float bl = bias ? bias[lane] : 0.f;
    for (int d = wid; d < n; d += nw) {
        const int beg = rowptr[d], end = rowptr[d + 1];
        float acc = 0.f;
        for (int base = beg; base < end; base += 64) {
            const int m = min(64, end - base);
            float2 rec = (lane < m) ? csr[base + lane] : make_float2(0.f, 0.f);
            int   sv = __float_as_int(rec.x);
            for (int j = 0; j < m; ++j) {
                int   s = __shfl(sv, j);
                float w = __shfl(rec.y, j);
                acc += w * h[s * 64 + lane];
            }
        }
        const float di = dinv[d];
        out[d * 64 + lane] = acc * di + h[d * 64 + lane] * di * di + bl;
    }
}

extern "C" void kernel_launch(void* const* d_in, const int* in_sizes, int n_in,
                              void* d_out, int out_size, void* d_ws, size_t ws_size,
                              hipStream_t stream) {
    const float* x  = (const float*)d_in[0];
    const int*   ei = (const int*)d_in[1];
    const float* W1 = (const float*)d_in[2];
    const float* b1 = (const float*)d_in[3];
    const float* W2 = (const float*)d_in[4];
    const float* b2 = (const float*)d_in[5];
    float* out = (float*)d_out;

    const int n = in_sizes[0] / 128;   // 50000
    const int E = in_sizes[1] / 2;     // 800000
    const int* src = ei;
    const int* dst = ei + E;
    const int nb = (n + 1023) / 1024;  // scan blocks

    char* ws = (char*)d_ws;
    size_t off = 0;
    auto alloc = [&](size_t bytes) { void* p = ws + off; off = (off + bytes + 255) & ~(size_t)255; return p; };
    int*    deg    = (int*)alloc((size_t)n * 4);
    float*  dinv   = (float*)alloc((size_t)n * 4);
    int*    rowptr = (int*)alloc((size_t)(n + 1) * 4);
    int*    cursor = (int*)alloc((size_t)n * 4);
    int*    bsum   = (int*)alloc((size_t)nb * 4);
    int*    boff   = (int*)alloc((size_t)nb * 4);
    float2* csr    = (float2*)alloc((size_t)E * 8);
    float*  h      = (float*)alloc((size_t)n * 64 * 4);
    float*  out1   = (float*)alloc((size_t)n * 64 * 4);
    (void)ws_size; (void)n_in; (void)out_size;

    hipMemsetAsync(deg, 0, (size_t)n * 4, stream);
    k_deg      <<<(E + 255) / 256, 256, 0, stream>>>(dst, deg, E);
    k_dinv     <<<(n + 255) / 256, 256, 0, stream>>>(deg, dinv, n);
    k_bsum     <<<nb, 1024, 0, stream>>>(deg, bsum, n);
    k_sbsum    <<<1, 64, 0, stream>>>(bsum, boff, nb);
    k_scanfinal<<<nb, 1024, 0, stream>>>(deg, boff, rowptr, cursor, n);
    k_scatter  <<<(E + 255) / 256, 256, 0, stream>>>(src, dst, dinv, cursor, csr, E);

    k_gemm1 <<<1024, 256, 0, stream>>>(x, W1, h, n);
    k_aggcsr<<<2048, 256, 0, stream>>>(rowptr, csr, dinv, h, b1, out1, n);

    k_gemm2 <<<1024, 256, 0, stream>>>(out1, W2, h, n);
    k_aggcsr<<<2048, 256, 0, stream>>>(rowptr, csr, dinv, h, b2, out, n);
}

// Round 4
// 234.802 us; speedup vs baseline: 2.1413x; 1.3593x over previous
//
#include <hip/hip_runtime.h>

// GCN 2-layer forward. CSR-by-dst aggregation (no f32 atomics) +
// MFMA bf16-split GEMMs (x@W via hi*hi + hi*lo + lo*hi, fp32-level accuracy).

typedef __bf16 bf16x8 __attribute__((ext_vector_type(8)));
typedef float  f32x4  __attribute__((ext_vector_type(4)));

__device__ __forceinline__ unsigned short f2bf(float f) {
    unsigned u = __float_as_uint(f);
    unsigned r = u + 0x7fff + ((u >> 16) & 1);   // round-nearest-even to bf16
    return (unsigned short)(r >> 16);
}
__device__ __forceinline__ float bf2f(unsigned short h) {
    return __uint_as_float(((unsigned)h) << 16);
}

__global__ void k_deg(const int* __restrict__ dst, int* __restrict__ deg, int E) {
    int i = blockIdx.x * blockDim.x + threadIdx.x;
    if (i < E) atomicAdd(&deg[dst[i]], 1);
}

__global__ void k_dinv(const int* __restrict__ deg, float* __restrict__ dinv, int n) {
    int i = blockIdx.x * blockDim.x + threadIdx.x;
    if (i < n) dinv[i] = rsqrtf((float)(deg[i] + 1));  // +1 = self-loop
}

__global__ __launch_bounds__(1024) void k_bsum(const int* __restrict__ deg,
                                               int* __restrict__ bsum, int n) {
    __shared__ int red[16];
    const int t = threadIdx.x;
    const int i = blockIdx.x * 1024 + t;
    int v = (i < n) ? deg[i] : 0;
#pragma unroll
    for (int o = 32; o; o >>= 1) v += __shfl_down(v, o);
    if ((t & 63) == 0) red[t >> 6] = v;
    __syncthreads();
    if (t == 0) {
        int s = 0;
#pragma unroll
        for (int w = 0; w < 16; ++w) s += red[w];
        bsum[blockIdx.x] = s;
    }
}

__global__ void k_sbsum(const int* __restrict__ bsum, int* __restrict__ boff, int nb) {
    if (threadIdx.x == 0 && blockIdx.x == 0) {
        int run = 0;
        for (int i = 0; i < nb; ++i) { boff[i] = run; run += bsum[i]; }
    }
}

__global__ __launch_bounds__(1024) void k_scanfinal(
    const int* __restrict__ deg, const int* __restrict__ boff,
    int* __restrict__ rowptr, int* __restrict__ cursor, int n) {
    __shared__ int sh[1024];
    const int t = threadIdx.x;
    const int i = blockIdx.x * 1024 + t;
    const int v = (i < n) ? deg[i] : 0;
    sh[t] = v;
    __syncthreads();
#pragma unroll
    for (int o = 1; o < 1024; o <<= 1) {
        int add = (t >= o) ? sh[t - o] : 0;
        __syncthreads();
        sh[t] += add;
        __syncthreads();
    }
    const int base = boff[blockIdx.x];
    const int excl = base + sh[t] - v;
    if (i < n) { rowptr[i] = excl; cursor[i] = excl; }
    if (i == n - 1) rowptr[n] = excl + v;   // == E
}

__global__ void k_scatter(const int* __restrict__ src, const int* __restrict__ dst,
                          const float* __restrict__ dinv, int* __restrict__ cursor,
                          float2* __restrict__ csr, int E) {
    int e = blockIdx.x * blockDim.x + threadIdx.x;
    if (e < E) {
        int s = src[e], d = dst[e];
        int pos = atomicAdd(&cursor[d], 1);
        csr[pos] = make_float2(__int_as_float(s), dinv[s]);
    }
}

// Pre-split W[K][64] into MFMA-frag-ordered hi/lo bf16 buffer:
// out[(((part*T + t)*4 + ct)*64 + lane)*8 + j] where
// lane = g*16 + (c&15), g = (k&31)>>3, j = k&7, t = k>>5, ct = c>>4.
__global__ void k_wsplit(const float* __restrict__ W, unsigned short* __restrict__ out, int K) {
    int i = blockIdx.x * blockDim.x + threadIdx.x;
    if (i >= K * 64) return;
    int k = i >> 6, c = i & 63;
    float v = W[k * 64 + c];
    unsigned short hi = f2bf(v);
    unsigned short lo = f2bf(v - bf2f(hi));
    int T = K / 32;
    int t = k >> 5, kk = k & 31, g = kk >> 3, j = kk & 7;
    int ct = c >> 4, lane = g * 16 + (c & 15);
    out[(((size_t)(0 * T + t) * 4 + ct) * 64 + lane) * 8 + j] = hi;
    out[(((size_t)(1 * T + t) * 4 + ct) * 64 + lane) * 8 + j] = lo;
}

// C[n x 64] = A[n x K] @ W[K x 64] via bf16-split MFMA. One wave per 16 rows.
// No LDS, no barriers. A/B frags loaded with identical per-lane k-mapping
// (layout deviations cancel); C/D mapping is the m89-verified one.
template<int K, bool LEAKY>
__global__ __launch_bounds__(256) void k_gemm_mfma(
    const float* __restrict__ A, const unsigned short* __restrict__ Ws,
    float* __restrict__ C, int n) {
    constexpr int T = K / 32;
    const int lane = threadIdx.x & 63;
    const int w = blockIdx.x * 4 + (threadIdx.x >> 6);
    const int r0 = w * 16;
    if (r0 >= n) return;
    const int g = lane >> 4, rA = lane & 15;

    bf16x8 ahi[T], alo[T];
    const float* arow = A + (size_t)(r0 + rA) * K + g * 8;
#pragma unroll
    for (int t = 0; t < T; ++t) {
        float4 v0 = *(const float4*)(arow + t * 32);
        float4 v1 = *(const float4*)(arow + t * 32 + 4);
        float f[8] = {v0.x, v0.y, v0.z, v0.w, v1.x, v1.y, v1.z, v1.w};
        union { unsigned short u[8]; bf16x8 v; } H, L;
#pragma unroll
        for (int j = 0; j < 8; ++j) {
            float x = f[j];
            if (LEAKY) x = x > 0.f ? x : 0.01f * x;
            unsigned short h = f2bf(x);
            H.u[j] = h;
            L.u[j] = f2bf(x - bf2f(h));
        }
        ahi[t] = H.v; alo[t] = L.v;
    }

    f32x4 acc[4];
#pragma unroll
    for (int ct = 0; ct < 4; ++ct) acc[ct] = (f32x4){0.f, 0.f, 0.f, 0.f};

#pragma unroll
    for (int ct = 0; ct < 4; ++ct) {
#pragma unroll
        for (int t = 0; t < T; ++t) {
            union { uint4 q; bf16x8 v; } Bh, Bl;
            Bh.q = *(const uint4*)(Ws + (((size_t)(0 * T + t) * 4 + ct) * 64 + lane) * 8);
            Bl.q = *(const uint4*)(Ws + (((size_t)(1 * T + t) * 4 + ct) * 64 + lane) * 8);
            acc[ct] = __builtin_amdgcn_mfma_f32_16x16x32_bf16(ahi[t], Bh.v, acc[ct], 0, 0, 0);
            acc[ct] = __builtin_amdgcn_mfma_f32_16x16x32_bf16(ahi[t], Bl.v, acc[ct], 0, 0, 0);
            acc[ct] = __builtin_amdgcn_mfma_f32_16x16x32_bf16(alo[t], Bh.v, acc[ct], 0, 0, 0);
        }
    }

    float* crow = C + (size_t)(r0 + g * 4) * 64 + rA;
#pragma unroll
    for (int ct = 0; ct < 4; ++ct)
#pragma unroll
        for (int r = 0; r < 4; ++r)
            crow[(size_t)r * 64 + ct * 16] = acc[ct][r];
}

// out[d] = dinv[d] * sum_e w_e * h[s_e] + dinv[d]^2 * h[d] + bias
__global__ __launch_bounds__(256) void k_aggcsr(
    const int* __restrict__ rowptr, const float2* __restrict__ csr,
    const float* __restrict__ dinv, const float* __restrict__ h,
    const float* __restrict__ bias, float* __restrict__ out, int n) {
    const int lane = threadIdx.x & 63;
    const int wid  = blockIdx.x * 4 + (threadIdx.x >> 6);
    const int nw   = gridDim.x * 4;
    const float bl = bias ? bias[lane] : 0.f;
    for (int d = wid; d < n; d += nw) {
        const int beg = rowptr[d], end = rowptr[d + 1];
        float acc = 0.f;
        for (int base = beg; base < end; base += 64) {
            const int m = min(64, end - base);
            float2 rec = (lane < m) ? csr[base + lane] : make_float2(0.f, 0.f);
            int   sv = __float_as_int(rec.x);
            for (int j = 0; j < m; ++j) {
                int   s = __shfl(sv, j);
                float w = __shfl(rec.y, j);
                acc += w * h[s * 64 + lane];
            }
        }
        const float di = dinv[d];
        out[d * 64 + lane] = acc * di + h[d * 64 + lane] * di * di + bl;
    }
}

extern "C" void kernel_launch(void* const* d_in, const int* in_sizes, int n_in,
                              void* d_out, int out_size, void* d_ws, size_t ws_size,
                              hipStream_t stream) {
    const float* x  = (const float*)d_in[0];
    const int*   ei = (const int*)d_in[1];
    const float* W1 = (const float*)d_in[2];
    const float* b1 = (const float*)d_in[3];
    const float* W2 = (const float*)d_in[4];
    const float* b2 = (const float*)d_in[5];
    float* out = (float*)d_out;

    const int n = in_sizes[0] / 128;   // 50000
    const int E = in_sizes[1] / 2;     // 800000
    const int* src = ei;
    const int* dst = ei + E;
    const int nb = (n + 1023) / 1024;

    char* ws = (char*)d_ws;
    size_t off = 0;
    auto alloc = [&](size_t bytes) { void* p = ws + off; off = (off + bytes + 255) & ~(size_t)255; return p; };
    int*    deg    = (int*)alloc((size_t)n * 4);
    float*  dinv   = (float*)alloc((size_t)n * 4);
    int*    rowptr = (int*)alloc((size_t)(n + 1) * 4);
    int*    cursor = (int*)alloc((size_t)n * 4);
    int*    bsum   = (int*)alloc((size_t)nb * 4);
    int*    boff   = (int*)alloc((size_t)nb * 4);
    float2* csr    = (float2*)alloc((size_t)E * 8);
    float*  h      = (float*)alloc((size_t)n * 64 * 4);
    float*  out1   = (float*)alloc((size_t)n * 64 * 4);
    unsigned short* W1s = (unsigned short*)alloc((size_t)2 * 128 * 64 * 2);  // 32 KB
    unsigned short* W2s = (unsigned short*)alloc((size_t)2 * 64 * 64 * 2);   // 16 KB
    (void)ws_size; (void)n_in; (void)out_size;

    hipMemsetAsync(deg, 0, (size_t)n * 4, stream);
    k_deg      <<<(E + 255) / 256, 256, 0, stream>>>(dst, deg, E);
    k_dinv     <<<(n + 255) / 256, 256, 0, stream>>>(deg, dinv, n);
    k_bsum     <<<nb, 1024, 0, stream>>>(deg, bsum, n);
    k_sbsum    <<<1, 64, 0, stream>>>(bsum, boff, nb);
    k_scanfinal<<<nb, 1024, 0, stream>>>(deg, boff, rowptr, cursor, n);
    k_scatter  <<<(E + 255) / 256, 256, 0, stream>>>(src, dst, dinv, cursor, csr, E);
    k_wsplit   <<<(128 * 64 + 255) / 256, 256, 0, stream>>>(W1, W1s, 128);
    k_wsplit   <<<(64 * 64 + 255) / 256, 256, 0, stream>>>(W2, W2s, 64);

    const int gemmBlocks = (n / 16 + 3) / 4;   // one wave per 16 rows
    k_gemm_mfma<128, false><<<gemmBlocks, 256, 0, stream>>>(x, W1s, h, n);
    k_aggcsr<<<2048, 256, 0, stream>>>(rowptr, csr, dinv, h, b1, out1, n);

    k_gemm_mfma<64, true><<<gemmBlocks, 256, 0, stream>>>(out1, W2s, h, n);
    k_aggcsr<<<2048, 256, 0, stream>>>(rowptr, csr, dinv, h, b2, out, n);
}

// Round 5
// 188.098 us; speedup vs baseline: 2.6730x; 1.2483x over previous
//
#include <hip/hip_runtime.h>

// GCN 2-layer forward. CSR-by-dst aggregation (no f32 atomics) +
// MFMA bf16-split GEMMs (x@W via hi*hi + hi*lo + lo*hi, fp32-level accuracy).
// Aggregation uses wave-uniform dst: scalar-load (SMEM) record broadcast +
// 4-way unrolled gathers for memory-level parallelism.

typedef __bf16 bf16x8 __attribute__((ext_vector_type(8)));
typedef float  f32x4  __attribute__((ext_vector_type(4)));

__device__ __forceinline__ unsigned short f2bf(float f) {
    unsigned u = __float_as_uint(f);
    unsigned r = u + 0x7fff + ((u >> 16) & 1);   // round-nearest-even to bf16
    return (unsigned short)(r >> 16);
}
__device__ __forceinline__ float bf2f(unsigned short h) {
    return __uint_as_float(((unsigned)h) << 16);
}

__global__ void k_deg(const int* __restrict__ dst, int* __restrict__ deg, int E) {
    int i = blockIdx.x * blockDim.x + threadIdx.x;
    if (i < E) atomicAdd(&deg[dst[i]], 1);
}

__global__ void k_dinv(const int* __restrict__ deg, float* __restrict__ dinv, int n) {
    int i = blockIdx.x * blockDim.x + threadIdx.x;
    if (i < n) dinv[i] = rsqrtf((float)(deg[i] + 1));  // +1 = self-loop
}

__global__ __launch_bounds__(1024) void k_bsum(const int* __restrict__ deg,
                                               int* __restrict__ bsum, int n) {
    __shared__ int red[16];
    const int t = threadIdx.x;
    const int i = blockIdx.x * 1024 + t;
    int v = (i < n) ? deg[i] : 0;
#pragma unroll
    for (int o = 32; o; o >>= 1) v += __shfl_down(v, o);
    if ((t & 63) == 0) red[t >> 6] = v;
    __syncthreads();
    if (t == 0) {
        int s = 0;
#pragma unroll
        for (int w = 0; w < 16; ++w) s += red[w];
        bsum[blockIdx.x] = s;
    }
}

__global__ void k_sbsum(const int* __restrict__ bsum, int* __restrict__ boff, int nb) {
    if (threadIdx.x == 0 && blockIdx.x == 0) {
        int run = 0;
        for (int i = 0; i < nb; ++i) { boff[i] = run; run += bsum[i]; }
    }
}

__global__ __launch_bounds__(1024) void k_scanfinal(
    const int* __restrict__ deg, const int* __restrict__ boff,
    int* __restrict__ rowptr, int* __restrict__ cursor, int n) {
    __shared__ int sh[1024];
    const int t = threadIdx.x;
    const int i = blockIdx.x * 1024 + t;
    const int v = (i < n) ? deg[i] : 0;
    sh[t] = v;
    __syncthreads();
#pragma unroll
    for (int o = 1; o < 1024; o <<= 1) {
        int add = (t >= o) ? sh[t - o] : 0;
        __syncthreads();
        sh[t] += add;
        __syncthreads();
    }
    const int base = boff[blockIdx.x];
    const int excl = base + sh[t] - v;
    if (i < n) { rowptr[i] = excl; cursor[i] = excl; }
    if (i == n - 1) rowptr[n] = excl + v;   // == E
}

// scatter edge records grouped by dst: csr[pos] = (src, bits(dinv[src]))
__global__ void k_scatter(const int* __restrict__ src, const int* __restrict__ dst,
                          const float* __restrict__ dinv, int* __restrict__ cursor,
                          int2* __restrict__ csr, int E) {
    int e = blockIdx.x * blockDim.x + threadIdx.x;
    if (e < E) {
        int s = src[e], d = dst[e];
        int pos = atomicAdd(&cursor[d], 1);
        csr[pos] = make_int2(s, __float_as_int(dinv[s]));
    }
}

// Pre-split W[K][64] into MFMA-frag-ordered hi/lo bf16 buffer.
__global__ void k_wsplit(const float* __restrict__ W, unsigned short* __restrict__ out, int K) {
    int i = blockIdx.x * blockDim.x + threadIdx.x;
    if (i >= K * 64) return;
    int k = i >> 6, c = i & 63;
    float v = W[k * 64 + c];
    unsigned short hi = f2bf(v);
    unsigned short lo = f2bf(v - bf2f(hi));
    int T = K / 32;
    int t = k >> 5, kk = k & 31, g = kk >> 3, j = kk & 7;
    int ct = c >> 4, lane = g * 16 + (c & 15);
    out[(((size_t)(0 * T + t) * 4 + ct) * 64 + lane) * 8 + j] = hi;
    out[(((size_t)(1 * T + t) * 4 + ct) * 64 + lane) * 8 + j] = lo;
}

// C[n x 64] = A[n x K] @ W[K x 64] via bf16-split MFMA. One wave per 16 rows.
template<int K, bool LEAKY>
__global__ __launch_bounds__(256) void k_gemm_mfma(
    const float* __restrict__ A, const unsigned short* __restrict__ Ws,
    float* __restrict__ C, int n) {
    constexpr int T = K / 32;
    const int lane = threadIdx.x & 63;
    const int w = blockIdx.x * 4 + (threadIdx.x >> 6);
    const int r0 = w * 16;
    if (r0 >= n) return;
    const int g = lane >> 4, rA = lane & 15;

    bf16x8 ahi[T], alo[T];
    const float* arow = A + (size_t)(r0 + rA) * K + g * 8;
#pragma unroll
    for (int t = 0; t < T; ++t) {
        float4 v0 = *(const float4*)(arow + t * 32);
        float4 v1 = *(const float4*)(arow + t * 32 + 4);
        float f[8] = {v0.x, v0.y, v0.z, v0.w, v1.x, v1.y, v1.z, v1.w};
        union { unsigned short u[8]; bf16x8 v; } H, L;
#pragma unroll
        for (int j = 0; j < 8; ++j) {
            float x = f[j];
            if (LEAKY) x = x > 0.f ? x : 0.01f * x;
            unsigned short h = f2bf(x);
            H.u[j] = h;
            L.u[j] = f2bf(x - bf2f(h));
        }
        ahi[t] = H.v; alo[t] = L.v;
    }

    f32x4 acc[4];
#pragma unroll
    for (int ct = 0; ct < 4; ++ct) acc[ct] = (f32x4){0.f, 0.f, 0.f, 0.f};

#pragma unroll
    for (int ct = 0; ct < 4; ++ct) {
#pragma unroll
        for (int t = 0; t < T; ++t) {
            union { uint4 q; bf16x8 v; } Bh, Bl;
            Bh.q = *(const uint4*)(Ws + (((size_t)(0 * T + t) * 4 + ct) * 64 + lane) * 8);
            Bl.q = *(const uint4*)(Ws + (((size_t)(1 * T + t) * 4 + ct) * 64 + lane) * 8);
            acc[ct] = __builtin_amdgcn_mfma_f32_16x16x32_bf16(ahi[t], Bh.v, acc[ct], 0, 0, 0);
            acc[ct] = __builtin_amdgcn_mfma_f32_16x16x32_bf16(ahi[t], Bl.v, acc[ct], 0, 0, 0);
            acc[ct] = __builtin_amdgcn_mfma_f32_16x16x32_bf16(alo[t], Bh.v, acc[ct], 0, 0, 0);
        }
    }

    float* crow = C + (size_t)(r0 + g * 4) * 64 + rA;
#pragma unroll
    for (int ct = 0; ct < 4; ++ct)
#pragma unroll
        for (int r = 0; r < 4; ++r)
            crow[(size_t)r * 64 + ct * 16] = acc[ct][r];
}

// out[d] = dinv[d] * sum_e w_e * h[s_e] + dinv[d]^2 * h[d] + bias
// One wave per dst row. d is wave-uniform -> csr records come in via scalar
// loads (SMEM broadcast); 4-way unroll gives 4 gathers in flight.
__global__ __launch_bounds__(256) void k_aggcsr(
    const int* __restrict__ rowptr, const int2* __restrict__ csr,
    const float* __restrict__ dinv, const float* __restrict__ h,
    const float* __restrict__ bias, float* __restrict__ out, int n) {
    const int lane = threadIdx.x & 63;
    const int wid  = blockIdx.x * 4 + (threadIdx.x >> 6);
    const int nw   = gridDim.x * 4;
    const float bl = bias[lane];
    for (int dd = wid; dd < n; dd += nw) {
        const int d = __builtin_amdgcn_readfirstlane(dd);
        const int beg = rowptr[d], end = rowptr[d + 1];
        float a0 = 0.f, a1 = 0.f, a2 = 0.f, a3 = 0.f;
        int j = beg;
        for (; j + 4 <= end; j += 4) {
            int2 r0 = csr[j + 0];
            int2 r1 = csr[j + 1];
            int2 r2 = csr[j + 2];
            int2 r3 = csr[j + 3];
            a0 += __int_as_float(r0.y) * h[(size_t)r0.x * 64 + lane];
            a1 += __int_as_float(r1.y) * h[(size_t)r1.x * 64 + lane];
            a2 += __int_as_float(r2.y) * h[(size_t)r2.x * 64 + lane];
            a3 += __int_as_float(r3.y) * h[(size_t)r3.x * 64 + lane];
        }
        for (; j < end; ++j) {
            int2 r = csr[j];
            a0 += __int_as_float(r.y) * h[(size_t)r.x * 64 + lane];
        }
        const float di = dinv[d];
        const float acc = (a0 + a1) + (a2 + a3);
        out[(size_t)d * 64 + lane] = acc * di + h[(size_t)d * 64 + lane] * di * di + bl;
    }
}

extern "C" void kernel_launch(void* const* d_in, const int* in_sizes, int n_in,
                              void* d_out, int out_size, void* d_ws, size_t ws_size,
                              hipStream_t stream) {
    const float* x  = (const float*)d_in[0];
    const int*   ei = (const int*)d_in[1];
    const float* W1 = (const float*)d_in[2];
    const float* b1 = (const float*)d_in[3];
    const float* W2 = (const float*)d_in[4];
    const float* b2 = (const float*)d_in[5];
    float* out = (float*)d_out;

    const int n = in_sizes[0] / 128;   // 50000
    const int E = in_sizes[1] / 2;     // 800000
    const int* src = ei;
    const int* dst = ei + E;
    const int nb = (n + 1023) / 1024;

    char* ws = (char*)d_ws;
    size_t off = 0;
    auto alloc = [&](size_t bytes) { void* p = ws + off; off = (off + bytes + 255) & ~(size_t)255; return p; };
    int*    deg    = (int*)alloc((size_t)n * 4);
    float*  dinv   = (float*)alloc((size_t)n * 4);
    int*    rowptr = (int*)alloc((size_t)(n + 1) * 4);
    int*    cursor = (int*)alloc((size_t)n * 4);
    int*    bsum   = (int*)alloc((size_t)nb * 4);
    int*    boff   = (int*)alloc((size_t)nb * 4);
    int2*   csr    = (int2*)alloc((size_t)E * 8);
    float*  h      = (float*)alloc((size_t)n * 64 * 4);
    float*  out1   = (float*)alloc((size_t)n * 64 * 4);
    unsigned short* W1s = (unsigned short*)alloc((size_t)2 * 128 * 64 * 2);  // 32 KB
    unsigned short* W2s = (unsigned short*)alloc((size_t)2 * 64 * 64 * 2);   // 16 KB
    (void)ws_size; (void)n_in; (void)out_size;

    hipMemsetAsync(deg, 0, (size_t)n * 4, stream);
    k_deg      <<<(E + 255) / 256, 256, 0, stream>>>(dst, deg, E);
    k_dinv     <<<(n + 255) / 256, 256, 0, stream>>>(deg, dinv, n);
    k_bsum     <<<nb, 1024, 0, stream>>>(deg, bsum, n);
    k_sbsum    <<<1, 64, 0, stream>>>(bsum, boff, nb);
    k_scanfinal<<<nb, 1024, 0, stream>>>(deg, boff, rowptr, cursor, n);
    k_scatter  <<<(E + 255) / 256, 256, 0, stream>>>(src, dst, dinv, cursor, csr, E);
    k_wsplit   <<<(128 * 64 + 255) / 256, 256, 0, stream>>>(W1, W1s, 128);
    k_wsplit   <<<(64 * 64 + 255) / 256, 256, 0, stream>>>(W2, W2s, 64);

    const int gemmBlocks = (n / 16 + 3) / 4;   // one wave per 16 rows
    k_gemm_mfma<128, false><<<gemmBlocks, 256, 0, stream>>>(x, W1s, h, n);
    k_aggcsr<<<2048, 256, 0, stream>>>(rowptr, csr, dinv, h, b1, out1, n);

    k_gemm_mfma<64, true><<<gemmBlocks, 256, 0, stream>>>(out1, W2s, h, n);
    k_aggcsr<<<2048, 256, 0, stream>>>(rowptr, csr, dinv, h, b2, out, n);
}

// Round 6
// 129.773 us; speedup vs baseline: 3.8743x; 1.4494x over previous
//
#include <hip/hip_runtime.h>

// GCN 2-layer forward.
// Two-stage bucket partition (no global atomics, line-friendly writes) builds
// node-grouped CSR + rowptr + dinv; MFMA bf16-split GEMMs with dinv-prescaled
// epilogue (hs = h*dinv); pull-aggregation with wave-uniform dst (scalar
// record loads) and 4-way unrolled gathers.

#define NBC   128          // partition blocks (stage-1)
#define BSH   7            // bucket shift: 128 nodes / bucket
#define NBMAX 512          // max buckets supported (n <= 65536)

typedef __bf16 bf16x8 __attribute__((ext_vector_type(8)));
typedef float  f32x4  __attribute__((ext_vector_type(4)));

__device__ __forceinline__ unsigned short f2bf(float f) {
    unsigned u = __float_as_uint(f);
    unsigned r = u + 0x7fff + ((u >> 16) & 1);   // round-nearest-even to bf16
    return (unsigned short)(r >> 16);
}
__device__ __forceinline__ float bf2f(unsigned short h) {
    return __uint_as_float(((unsigned)h) << 16);
}

// stage-1 histogram: T[bucket][block] = #edges of this block's chunk in bucket
__global__ __launch_bounds__(256) void k_hist1(const int* __restrict__ dst,
                                               int* __restrict__ T, int E, int nbuck) {
    __shared__ int hist[NBMAX];
    for (int i = threadIdx.x; i < nbuck; i += 256) hist[i] = 0;
    __syncthreads();
    const int per = (E + NBC - 1) / NBC;
    const int beg = blockIdx.x * per, end = min(beg + per, E);
    for (int i = beg + threadIdx.x; i < end; i += 256)
        atomicAdd(&hist[dst[i] >> BSH], 1);
    __syncthreads();
    for (int b = threadIdx.x; b < nbuck; b += 256)
        T[b * NBC + blockIdx.x] = hist[b];
}

// hierarchical exclusive scan over m elements (proven round-3 structure)
__global__ __launch_bounds__(1024) void k_bsum(const int* __restrict__ in,
                                               int* __restrict__ bsum, int m) {
    __shared__ int red[16];
    const int t = threadIdx.x;
    const int i = blockIdx.x * 1024 + t;
    int v = (i < m) ? in[i] : 0;
#pragma unroll
    for (int o = 32; o; o >>= 1) v += __shfl_down(v, o);
    if ((t & 63) == 0) red[t >> 6] = v;
    __syncthreads();
    if (t == 0) {
        int s = 0;
#pragma unroll
        for (int w = 0; w < 16; ++w) s += red[w];
        bsum[blockIdx.x] = s;
    }
}

__global__ void k_sbsum(const int* __restrict__ bsum, int* __restrict__ boff, int nb) {
    if (threadIdx.x == 0 && blockIdx.x == 0) {
        int run = 0;
        for (int i = 0; i < nb; ++i) { boff[i] = run; run += bsum[i]; }
    }
}

__global__ __launch_bounds__(1024) void k_scanexc(
    const int* __restrict__ in, const int* __restrict__ boff,
    int* __restrict__ out, int m) {
    __shared__ int sh[1024];
    const int t = threadIdx.x;
    const int i = blockIdx.x * 1024 + t;
    const int v = (i < m) ? in[i] : 0;
    sh[t] = v;
    __syncthreads();
#pragma unroll
    for (int o = 1; o < 1024; o <<= 1) {
        int add = (t >= o) ? sh[t - o] : 0;
        __syncthreads();
        sh[t] += add;
        __syncthreads();
    }
    if (i < m) out[i] = boff[blockIdx.x] + sh[t] - v;
}

// stage-1 partition: block writes packed (d&127)<<17|src into its private
// contiguous run per bucket. Only LDS atomics; writes are L2-line-friendly.
__global__ __launch_bounds__(256) void k_part1(
    const int* __restrict__ src, const int* __restrict__ dst,
    const int* __restrict__ Toff, unsigned* __restrict__ stage, int E, int nbuck) {
    __shared__ int base[NBMAX];
    __shared__ int cnt[NBMAX];
    for (int i = threadIdx.x; i < nbuck; i += 256) {
        base[i] = Toff[i * NBC + blockIdx.x];
        cnt[i] = 0;
    }
    __syncthreads();
    const int per = (E + NBC - 1) / NBC;
    const int beg = blockIdx.x * per, end = min(beg + per, E);
    for (int i = beg + threadIdx.x; i < end; i += 256) {
        int d = dst[i], s = src[i];
        int b = d >> BSH;
        int p = atomicAdd(&cnt[b], 1);
        stage[base[b] + p] = ((unsigned)(d & 127) << 17) | (unsigned)s;
    }
}

// stage-2: one block per bucket. Pass 1 counts per node -> rowptr + dinv
// (degree falls out for free); pass 2 scatters src into node-grouped csr
// within the bucket's hot ~8KB region.
__global__ __launch_bounds__(256) void k_part2(
    const int* __restrict__ Toff, const unsigned* __restrict__ stage,
    int* __restrict__ csr, int* __restrict__ rowptr, float* __restrict__ dinv,
    int n, int E, int nbuck) {
    __shared__ int cnt[128], sc[128], curs[128];
    __shared__ int rbs, res;
    const int t = threadIdx.x;
    const int b = blockIdx.x;
    if (t < 128) cnt[t] = 0;
    if (t == 0) {
        rbs = Toff[b * NBC];
        res = (b == nbuck - 1) ? E : Toff[(b + 1) * NBC];
    }
    __syncthreads();
    const int rb = rbs, re = res;
    for (int i = rb + t; i < re; i += 256)
        atomicAdd(&cnt[(stage[i] >> 17) & 127], 1);
    __syncthreads();
    if (t < 128) sc[t] = cnt[t];
    __syncthreads();
#pragma unroll
    for (int o = 1; o < 128; o <<= 1) {
        int add = (t < 128 && t >= o) ? sc[t - o] : 0;
        __syncthreads();
        if (t < 128) sc[t] += add;
        __syncthreads();
    }
    if (t < 128) {
        const int excl = rb + sc[t] - cnt[t];
        curs[t] = excl;
        const int gi = b * 128 + t;
        if (gi < n) {
            rowptr[gi] = excl;
            dinv[gi] = rsqrtf((float)cnt[t] + 1.f);   // +1 = self-loop
            if (gi == n - 1) rowptr[n] = rb + sc[t];  // == E
        }
    }
    __syncthreads();
    for (int i = rb + t; i < re; i += 256) {
        unsigned r = stage[i];
        int p = atomicAdd(&curs[(r >> 17) & 127], 1);
        csr[p] = (int)(r & 0x1FFFF);
    }
}

// Pre-split W[K][64] into MFMA-frag-ordered hi/lo bf16 buffer.
__global__ void k_wsplit(const float* __restrict__ W, unsigned short* __restrict__ out, int K) {
    int i = blockIdx.x * blockDim.x + threadIdx.x;
    if (i >= K * 64) return;
    int k = i >> 6, c = i & 63;
    float v = W[k * 64 + c];
    unsigned short hi = f2bf(v);
    unsigned short lo = f2bf(v - bf2f(hi));
    int T = K / 32;
    int t = k >> 5, kk = k & 31, g = kk >> 3, j = kk & 7;
    int ct = c >> 4, lane = g * 16 + (c & 15);
    out[(((size_t)(0 * T + t) * 4 + ct) * 64 + lane) * 8 + j] = hi;
    out[(((size_t)(1 * T + t) * 4 + ct) * 64 + lane) * 8 + j] = lo;
}

// hs[n x 64] = (A[n x K] @ W[K x 64]) * dinv[row] via bf16-split MFMA.
// One wave per 16 rows, no LDS, no barriers.
template<int K, bool LEAKY>
__global__ __launch_bounds__(256) void k_gemm_mfma(
    const float* __restrict__ A, const unsigned short* __restrict__ Ws,
    const float* __restrict__ dinv, float* __restrict__ C, int n) {
    constexpr int T = K / 32;
    const int lane = threadIdx.x & 63;
    const int w = blockIdx.x * 4 + (threadIdx.x >> 6);
    const int r0 = w * 16;
    if (r0 >= n) return;
    const int g = lane >> 4, rA = lane & 15;

    bf16x8 ahi[T], alo[T];
    const float* arow = A + (size_t)(r0 + rA) * K + g * 8;
#pragma unroll
    for (int t = 0; t < T; ++t) {
        float4 v0 = *(const float4*)(arow + t * 32);
        float4 v1 = *(const float4*)(arow + t * 32 + 4);
        float f[8] = {v0.x, v0.y, v0.z, v0.w, v1.x, v1.y, v1.z, v1.w};
        union { unsigned short u[8]; bf16x8 v; } H, L;
#pragma unroll
        for (int j = 0; j < 8; ++j) {
            float x = f[j];
            if (LEAKY) x = x > 0.f ? x : 0.01f * x;
            unsigned short h = f2bf(x);
            H.u[j] = h;
            L.u[j] = f2bf(x - bf2f(h));
        }
        ahi[t] = H.v; alo[t] = L.v;
    }

    f32x4 acc[4];
#pragma unroll
    for (int ct = 0; ct < 4; ++ct) acc[ct] = (f32x4){0.f, 0.f, 0.f, 0.f};

#pragma unroll
    for (int ct = 0; ct < 4; ++ct) {
#pragma unroll
        for (int t = 0; t < T; ++t) {
            union { uint4 q; bf16x8 v; } Bh, Bl;
            Bh.q = *(const uint4*)(Ws + (((size_t)(0 * T + t) * 4 + ct) * 64 + lane) * 8);
            Bl.q = *(const uint4*)(Ws + (((size_t)(1 * T + t) * 4 + ct) * 64 + lane) * 8);
            acc[ct] = __builtin_amdgcn_mfma_f32_16x16x32_bf16(ahi[t], Bh.v, acc[ct], 0, 0, 0);
            acc[ct] = __builtin_amdgcn_mfma_f32_16x16x32_bf16(ahi[t], Bl.v, acc[ct], 0, 0, 0);
            acc[ct] = __builtin_amdgcn_mfma_f32_16x16x32_bf16(alo[t], Bh.v, acc[ct], 0, 0, 0);
        }
    }

    float dv[4];
#pragma unroll
    for (int r = 0; r < 4; ++r) dv[r] = dinv[r0 + g * 4 + r];

    float* crow = C + (size_t)(r0 + g * 4) * 64 + rA;
#pragma unroll
    for (int ct = 0; ct < 4; ++ct)
#pragma unroll
        for (int r = 0; r < 4; ++r)
            crow[(size_t)r * 64 + ct * 16] = acc[ct][r] * dv[r];
}

// out[d] = (sum_e hs[s_e] + hs[d]) * dinv[d] + bias
// One wave per dst row; d wave-uniform -> csr loads are scalar (SMEM);
// 4-way unroll keeps 4 gathers in flight.
__global__ __launch_bounds__(256) void k_aggcsr(
    const int* __restrict__ rowptr, const int* __restrict__ csr,
    const float* __restrict__ dinv, const float* __restrict__ hs,
    const float* __restrict__ bias, float* __restrict__ out, int n) {
    const int lane = threadIdx.x & 63;
    const int wid  = blockIdx.x * 4 + (threadIdx.x >> 6);
    const int nw   = gridDim.x * 4;
    const float bl = bias[lane];
    for (int dd = wid; dd < n; dd += nw) {
        const int d = __builtin_amdgcn_readfirstlane(dd);
        const int beg = rowptr[d], end = rowptr[d + 1];
        float a0 = 0.f, a1 = 0.f, a2 = 0.f, a3 = 0.f;
        int j = beg;
        for (; j + 4 <= end; j += 4) {
            int s0 = csr[j + 0];
            int s1 = csr[j + 1];
            int s2 = csr[j + 2];
            int s3 = csr[j + 3];
            a0 += hs[(size_t)s0 * 64 + lane];
            a1 += hs[(size_t)s1 * 64 + lane];
            a2 += hs[(size_t)s2 * 64 + lane];
            a3 += hs[(size_t)s3 * 64 + lane];
        }
        for (; j < end; ++j)
            a0 += hs[(size_t)csr[j] * 64 + lane];
        const float di = dinv[d];
        const float acc = (a0 + a1) + (a2 + a3);
        out[(size_t)d * 64 + lane] = (acc + hs[(size_t)d * 64 + lane]) * di + bl;
    }
}

extern "C" void kernel_launch(void* const* d_in, const int* in_sizes, int n_in,
                              void* d_out, int out_size, void* d_ws, size_t ws_size,
                              hipStream_t stream) {
    const float* x  = (const float*)d_in[0];
    const int*   ei = (const int*)d_in[1];
    const float* W1 = (const float*)d_in[2];
    const float* b1 = (const float*)d_in[3];
    const float* W2 = (const float*)d_in[4];
    const float* b2 = (const float*)d_in[5];
    float* out = (float*)d_out;

    const int n = in_sizes[0] / 128;   // 50000
    const int E = in_sizes[1] / 2;     // 800000
    const int* src = ei;
    const int* dst = ei + E;

    const int nbuck = (n + 127) >> BSH;        // 391
    const int m = nbuck * NBC;                 // 50048 table entries
    const int nb2 = (m + 1023) / 1024;         // 49 scan blocks

    char* ws = (char*)d_ws;
    size_t off = 0;
    auto alloc = [&](size_t bytes) { void* p = ws + off; off = (off + bytes + 255) & ~(size_t)255; return p; };
    int*      T      = (int*)alloc((size_t)m * 4);
    int*      Toff   = (int*)alloc((size_t)m * 4);
    int*      bsum   = (int*)alloc((size_t)nb2 * 4);
    int*      boff   = (int*)alloc((size_t)nb2 * 4);
    unsigned* stage  = (unsigned*)alloc((size_t)E * 4);
    int*      csr    = (int*)alloc((size_t)E * 4);
    int*      rowptr = (int*)alloc((size_t)(n + 1) * 4);
    float*    dinv   = (float*)alloc((size_t)n * 4);
    float*    hs     = (float*)alloc((size_t)n * 64 * 4);
    float*    out1   = (float*)alloc((size_t)n * 64 * 4);
    unsigned short* W1s = (unsigned short*)alloc((size_t)2 * 128 * 64 * 2);
    unsigned short* W2s = (unsigned short*)alloc((size_t)2 * 64 * 64 * 2);
    (void)ws_size; (void)n_in; (void)out_size;

    // CSR build: histogram -> scan -> 2-stage partition (no global atomics)
    k_hist1  <<<NBC, 256, 0, stream>>>(dst, T, E, nbuck);
    k_bsum   <<<nb2, 1024, 0, stream>>>(T, bsum, m);
    k_sbsum  <<<1, 64, 0, stream>>>(bsum, boff, nb2);
    k_scanexc<<<nb2, 1024, 0, stream>>>(T, boff, Toff, m);
    k_part1  <<<NBC, 256, 0, stream>>>(src, dst, Toff, stage, E, nbuck);
    k_part2  <<<nbuck, 256, 0, stream>>>(Toff, stage, csr, rowptr, dinv, n, E, nbuck);

    k_wsplit <<<(128 * 64 + 255) / 256, 256, 0, stream>>>(W1, W1s, 128);
    k_wsplit <<<(64 * 64 + 255) / 256, 256, 0, stream>>>(W2, W2s, 64);

    const int gemmBlocks = (n / 16 + 3) / 4;   // one wave per 16 rows
    k_gemm_mfma<128, false><<<gemmBlocks, 256, 0, stream>>>(x, W1s, dinv, hs, n);
    k_aggcsr<<<2048, 256, 0, stream>>>(rowptr, csr, dinv, hs, b1, out1, n);

    k_gemm_mfma<64, true><<<gemmBlocks, 256, 0, stream>>>(out1, W2s, dinv, hs, n);
    k_aggcsr<<<2048, 256, 0, stream>>>(rowptr, csr, dinv, hs, b2, out, n);
}

// Round 7
// 115.272 us; speedup vs baseline: 4.3617x; 1.1258x over previous
//
#include <hip/hip_runtime.h>
#include <hip/hip_fp16.h>

// GCN 2-layer forward.
// Two-stage bucket partition (no global atomics, line-friendly writes) builds
// node-grouped CSR + rowptr + dinv; MFMA bf16-split GEMMs with dinv-prescaled
// fp16 epilogue (hs = half(h*dinv)); pull-aggregation with wave-uniform dst
// (scalar record loads) and 8-way unrolled fp16 gathers (128B/edge).

#define NBC   128          // partition blocks (stage-1)
#define BSH   7            // bucket shift: 128 nodes / bucket
#define NBMAX 512          // max buckets supported (n <= 65536)

typedef __bf16 bf16x8 __attribute__((ext_vector_type(8)));
typedef float  f32x4  __attribute__((ext_vector_type(4)));

__device__ __forceinline__ unsigned short f2bf(float f) {
    unsigned u = __float_as_uint(f);
    unsigned r = u + 0x7fff + ((u >> 16) & 1);   // round-nearest-even to bf16
    return (unsigned short)(r >> 16);
}
__device__ __forceinline__ float bf2f(unsigned short h) {
    return __uint_as_float(((unsigned)h) << 16);
}

// stage-1 histogram: T[bucket][block] = #edges of this block's chunk in bucket
__global__ __launch_bounds__(256) void k_hist1(const int* __restrict__ dst,
                                               int* __restrict__ T, int E, int nbuck) {
    __shared__ int hist[NBMAX];
    for (int i = threadIdx.x; i < nbuck; i += 256) hist[i] = 0;
    __syncthreads();
    const int per = (E + NBC - 1) / NBC;
    const int beg = blockIdx.x * per, end = min(beg + per, E);
    for (int i = beg + threadIdx.x; i < end; i += 256)
        atomicAdd(&hist[dst[i] >> BSH], 1);
    __syncthreads();
    for (int b = threadIdx.x; b < nbuck; b += 256)
        T[b * NBC + blockIdx.x] = hist[b];
}

// hierarchical exclusive scan over m elements
__global__ __launch_bounds__(1024) void k_bsum(const int* __restrict__ in,
                                               int* __restrict__ bsum, int m) {
    __shared__ int red[16];
    const int t = threadIdx.x;
    const int i = blockIdx.x * 1024 + t;
    int v = (i < m) ? in[i] : 0;
#pragma unroll
    for (int o = 32; o; o >>= 1) v += __shfl_down(v, o);
    if ((t & 63) == 0) red[t >> 6] = v;
    __syncthreads();
    if (t == 0) {
        int s = 0;
#pragma unroll
        for (int w = 0; w < 16; ++w) s += red[w];
        bsum[blockIdx.x] = s;
    }
}

__global__ void k_sbsum(const int* __restrict__ bsum, int* __restrict__ boff, int nb) {
    if (threadIdx.x == 0 && blockIdx.x == 0) {
        int run = 0;
        for (int i = 0; i < nb; ++i) { boff[i] = run; run += bsum[i]; }
    }
}

__global__ __launch_bounds__(1024) void k_scanexc(
    const int* __restrict__ in, const int* __restrict__ boff,
    int* __restrict__ out, int m) {
    __shared__ int sh[1024];
    const int t = threadIdx.x;
    const int i = blockIdx.x * 1024 + t;
    const int v = (i < m) ? in[i] : 0;
    sh[t] = v;
    __syncthreads();
#pragma unroll
    for (int o = 1; o < 1024; o <<= 1) {
        int add = (t >= o) ? sh[t - o] : 0;
        __syncthreads();
        sh[t] += add;
        __syncthreads();
    }
    if (i < m) out[i] = boff[blockIdx.x] + sh[t] - v;
}

// stage-1 partition: block writes packed (d&127)<<17|src into its private
// contiguous run per bucket. Only LDS atomics; writes are L2-line-friendly.
__global__ __launch_bounds__(256) void k_part1(
    const int* __restrict__ src, const int* __restrict__ dst,
    const int* __restrict__ Toff, unsigned* __restrict__ stage, int E, int nbuck) {
    __shared__ int base[NBMAX];
    __shared__ int cnt[NBMAX];
    for (int i = threadIdx.x; i < nbuck; i += 256) {
        base[i] = Toff[i * NBC + blockIdx.x];
        cnt[i] = 0;
    }
    __syncthreads();
    const int per = (E + NBC - 1) / NBC;
    const int beg = blockIdx.x * per, end = min(beg + per, E);
    for (int i = beg + threadIdx.x; i < end; i += 256) {
        int d = dst[i], s = src[i];
        int b = d >> BSH;
        int p = atomicAdd(&cnt[b], 1);
        stage[base[b] + p] = ((unsigned)(d & 127) << 17) | (unsigned)s;
    }
}

// stage-2: one block per bucket. Pass 1 counts per node -> rowptr + dinv;
// pass 2 scatters src into node-grouped csr within the bucket's hot region.
__global__ __launch_bounds__(256) void k_part2(
    const int* __restrict__ Toff, const unsigned* __restrict__ stage,
    int* __restrict__ csr, int* __restrict__ rowptr, float* __restrict__ dinv,
    int n, int E, int nbuck) {
    __shared__ int cnt[128], sc[128], curs[128];
    __shared__ int rbs, res;
    const int t = threadIdx.x;
    const int b = blockIdx.x;
    if (t < 128) cnt[t] = 0;
    if (t == 0) {
        rbs = Toff[b * NBC];
        res = (b == nbuck - 1) ? E : Toff[(b + 1) * NBC];
    }
    __syncthreads();
    const int rb = rbs, re = res;
    for (int i = rb + t; i < re; i += 256)
        atomicAdd(&cnt[(stage[i] >> 17) & 127], 1);
    __syncthreads();
    if (t < 128) sc[t] = cnt[t];
    __syncthreads();
#pragma unroll
    for (int o = 1; o < 128; o <<= 1) {
        int add = (t < 128 && t >= o) ? sc[t - o] : 0;
        __syncthreads();
        if (t < 128) sc[t] += add;
        __syncthreads();
    }
    if (t < 128) {
        const int excl = rb + sc[t] - cnt[t];
        curs[t] = excl;
        const int gi = b * 128 + t;
        if (gi < n) {
            rowptr[gi] = excl;
            dinv[gi] = rsqrtf((float)cnt[t] + 1.f);   // +1 = self-loop
            if (gi == n - 1) rowptr[n] = rb + sc[t];  // == E
        }
    }
    __syncthreads();
    for (int i = rb + t; i < re; i += 256) {
        unsigned r = stage[i];
        int p = atomicAdd(&curs[(r >> 17) & 127], 1);
        csr[p] = (int)(r & 0x1FFFF);
    }
}

// Pre-split W[K][64] into MFMA-frag-ordered hi/lo bf16 buffer.
__global__ void k_wsplit(const float* __restrict__ W, unsigned short* __restrict__ out, int K) {
    int i = blockIdx.x * blockDim.x + threadIdx.x;
    if (i >= K * 64) return;
    int k = i >> 6, c = i & 63;
    float v = W[k * 64 + c];
    unsigned short hi = f2bf(v);
    unsigned short lo = f2bf(v - bf2f(hi));
    int T = K / 32;
    int t = k >> 5, kk = k & 31, g = kk >> 3, j = kk & 7;
    int ct = c >> 4, lane = g * 16 + (c & 15);
    out[(((size_t)(0 * T + t) * 4 + ct) * 64 + lane) * 8 + j] = hi;
    out[(((size_t)(1 * T + t) * 4 + ct) * 64 + lane) * 8 + j] = lo;
}

// hs[n x 64] = half((A[n x K] @ W[K x 64]) * dinv[row]) via bf16-split MFMA.
// One wave per 16 rows, no LDS, no barriers.
template<int K, bool LEAKY>
__global__ __launch_bounds__(256) void k_gemm_mfma(
    const float* __restrict__ A, const unsigned short* __restrict__ Ws,
    const float* __restrict__ dinv, __half* __restrict__ C, int n) {
    constexpr int T = K / 32;
    const int lane = threadIdx.x & 63;
    const int w = blockIdx.x * 4 + (threadIdx.x >> 6);
    const int r0 = w * 16;
    if (r0 >= n) return;
    const int g = lane >> 4, rA = lane & 15;

    bf16x8 ahi[T], alo[T];
    const float* arow = A + (size_t)(r0 + rA) * K + g * 8;
#pragma unroll
    for (int t = 0; t < T; ++t) {
        float4 v0 = *(const float4*)(arow + t * 32);
        float4 v1 = *(const float4*)(arow + t * 32 + 4);
        float f[8] = {v0.x, v0.y, v0.z, v0.w, v1.x, v1.y, v1.z, v1.w};
        union { unsigned short u[8]; bf16x8 v; } H, L;
#pragma unroll
        for (int j = 0; j < 8; ++j) {
            float x = f[j];
            if (LEAKY) x = x > 0.f ? x : 0.01f * x;
            unsigned short h = f2bf(x);
            H.u[j] = h;
            L.u[j] = f2bf(x - bf2f(h));
        }
        ahi[t] = H.v; alo[t] = L.v;
    }

    f32x4 acc[4];
#pragma unroll
    for (int ct = 0; ct < 4; ++ct) acc[ct] = (f32x4){0.f, 0.f, 0.f, 0.f};

#pragma unroll
    for (int ct = 0; ct < 4; ++ct) {
#pragma unroll
        for (int t = 0; t < T; ++t) {
            union { uint4 q; bf16x8 v; } Bh, Bl;
            Bh.q = *(const uint4*)(Ws + (((size_t)(0 * T + t) * 4 + ct) * 64 + lane) * 8);
            Bl.q = *(const uint4*)(Ws + (((size_t)(1 * T + t) * 4 + ct) * 64 + lane) * 8);
            acc[ct] = __builtin_amdgcn_mfma_f32_16x16x32_bf16(ahi[t], Bh.v, acc[ct], 0, 0, 0);
            acc[ct] = __builtin_amdgcn_mfma_f32_16x16x32_bf16(ahi[t], Bl.v, acc[ct], 0, 0, 0);
            acc[ct] = __builtin_amdgcn_mfma_f32_16x16x32_bf16(alo[t], Bh.v, acc[ct], 0, 0, 0);
        }
    }

    float dv[4];
#pragma unroll
    for (int r = 0; r < 4; ++r) dv[r] = dinv[r0 + g * 4 + r];

    __half* crow = C + (size_t)(r0 + g * 4) * 64 + rA;
#pragma unroll
    for (int ct = 0; ct < 4; ++ct)
#pragma unroll
        for (int r = 0; r < 4; ++r)
            crow[(size_t)r * 64 + ct * 16] = __float2half_rn(acc[ct][r] * dv[r]);
}

// out[d] = (sum_e hs[s_e] + hs[d]) * dinv[d] + bias
// One wave per dst row; d wave-uniform -> csr loads are scalar (SMEM);
// 8-way unroll keeps 8 fp16 gathers (128B each) in flight.
__global__ __launch_bounds__(256) void k_aggcsr(
    const int* __restrict__ rowptr, const int* __restrict__ csr,
    const float* __restrict__ dinv, const __half* __restrict__ hs,
    const float* __restrict__ bias, float* __restrict__ out, int n) {
    const int lane = threadIdx.x & 63;
    const int wid  = blockIdx.x * 4 + (threadIdx.x >> 6);
    const int nw   = gridDim.x * 4;
    const float bl = bias[lane];
    for (int dd = wid; dd < n; dd += nw) {
        const int d = __builtin_amdgcn_readfirstlane(dd);
        const int beg = rowptr[d], end = rowptr[d + 1];
        float a0 = 0.f, a1 = 0.f, a2 = 0.f, a3 = 0.f;
        float a4 = 0.f, a5 = 0.f, a6 = 0.f, a7 = 0.f;
        int j = beg;
        for (; j + 8 <= end; j += 8) {
            int s0 = csr[j + 0], s1 = csr[j + 1], s2 = csr[j + 2], s3 = csr[j + 3];
            int s4 = csr[j + 4], s5 = csr[j + 5], s6 = csr[j + 6], s7 = csr[j + 7];
            a0 += __half2float(hs[(size_t)s0 * 64 + lane]);
            a1 += __half2float(hs[(size_t)s1 * 64 + lane]);
            a2 += __half2float(hs[(size_t)s2 * 64 + lane]);
            a3 += __half2float(hs[(size_t)s3 * 64 + lane]);
            a4 += __half2float(hs[(size_t)s4 * 64 + lane]);
            a5 += __half2float(hs[(size_t)s5 * 64 + lane]);
            a6 += __half2float(hs[(size_t)s6 * 64 + lane]);
            a7 += __half2float(hs[(size_t)s7 * 64 + lane]);
        }
        for (; j < end; ++j)
            a0 += __half2float(hs[(size_t)csr[j] * 64 + lane]);
        const float di = dinv[d];
        const float acc = ((a0 + a1) + (a2 + a3)) + ((a4 + a5) + (a6 + a7));
        out[(size_t)d * 64 + lane] =
            (acc + __half2float(hs[(size_t)d * 64 + lane])) * di + bl;
    }
}

extern "C" void kernel_launch(void* const* d_in, const int* in_sizes, int n_in,
                              void* d_out, int out_size, void* d_ws, size_t ws_size,
                              hipStream_t stream) {
    const float* x  = (const float*)d_in[0];
    const int*   ei = (const int*)d_in[1];
    const float* W1 = (const float*)d_in[2];
    const float* b1 = (const float*)d_in[3];
    const float* W2 = (const float*)d_in[4];
    const float* b2 = (const float*)d_in[5];
    float* out = (float*)d_out;

    const int n = in_sizes[0] / 128;   // 50000
    const int E = in_sizes[1] / 2;     // 800000
    const int* src = ei;
    const int* dst = ei + E;

    const int nbuck = (n + 127) >> BSH;        // 391
    const int m = nbuck * NBC;                 // 50048 table entries
    const int nb2 = (m + 1023) / 1024;         // 49 scan blocks

    char* ws = (char*)d_ws;
    size_t off = 0;
    auto alloc = [&](size_t bytes) { void* p = ws + off; off = (off + bytes + 255) & ~(size_t)255; return p; };
    int*      T      = (int*)alloc((size_t)m * 4);
    int*      Toff   = (int*)alloc((size_t)m * 4);
    int*      bsum   = (int*)alloc((size_t)nb2 * 4);
    int*      boff   = (int*)alloc((size_t)nb2 * 4);
    unsigned* stage  = (unsigned*)alloc((size_t)E * 4);
    int*      csr    = (int*)alloc((size_t)E * 4);
    int*      rowptr = (int*)alloc((size_t)(n + 1) * 4);
    float*    dinv   = (float*)alloc((size_t)n * 4);
    __half*   hs     = (__half*)alloc((size_t)n * 64 * 2);
    float*    out1   = (float*)alloc((size_t)n * 64 * 4);
    unsigned short* W1s = (unsigned short*)alloc((size_t)2 * 128 * 64 * 2);
    unsigned short* W2s = (unsigned short*)alloc((size_t)2 * 64 * 64 * 2);
    (void)ws_size; (void)n_in; (void)out_size;

    // CSR build: histogram -> scan -> 2-stage partition (no global atomics)
    k_hist1  <<<NBC, 256, 0, stream>>>(dst, T, E, nbuck);
    k_bsum   <<<nb2, 1024, 0, stream>>>(T, bsum, m);
    k_sbsum  <<<1, 64, 0, stream>>>(bsum, boff, nb2);
    k_scanexc<<<nb2, 1024, 0, stream>>>(T, boff, Toff, m);
    k_part1  <<<NBC, 256, 0, stream>>>(src, dst, Toff, stage, E, nbuck);
    k_part2  <<<nbuck, 256, 0, stream>>>(Toff, stage, csr, rowptr, dinv, n, E, nbuck);

    k_wsplit <<<(128 * 64 + 255) / 256, 256, 0, stream>>>(W1, W1s, 128);
    k_wsplit <<<(64 * 64 + 255) / 256, 256, 0, stream>>>(W2, W2s, 64);

    const int gemmBlocks = (n / 16 + 3) / 4;   // one wave per 16 rows
    k_gemm_mfma<128, false><<<gemmBlocks, 256, 0, stream>>>(x, W1s, dinv, hs, n);
    k_aggcsr<<<2048, 256, 0, stream>>>(rowptr, csr, dinv, hs, b1, out1, n);

    k_gemm_mfma<64, true><<<gemmBlocks, 256, 0, stream>>>(out1, W2s, dinv, hs, n);
    k_aggcsr<<<2048, 256, 0, stream>>>(rowptr, csr, dinv, hs, b2, out, n);
}

// Round 8
// 111.277 us; speedup vs baseline: 4.5183x; 1.0359x over previous
//
#include <hip/hip_runtime.h>
#include <hip/hip_fp16.h>
#include <type_traits>

// GCN 2-layer forward.
// Two-stage bucket partition (no global atomics) builds node-grouped CSR +
// rowptr + dinv; part2 stages its bucket in LDS (single global pass, coalesced
// writeback). MFMA bf16-split GEMMs with dinv-prescaled fp16 epilogue
// (hs = half(h*dinv)); pull-aggregation with wave-uniform dst (scalar record
// loads) and 8-way unrolled fp16 gathers (128B/edge).

#define NBC   128          // partition blocks (stage-1)
#define BSH   7            // bucket shift: 128 nodes / bucket
#define NBMAX 512          // max buckets supported (n <= 65536)
#define CAP   8192         // part2 LDS record capacity (mean 2046, 136 sigma)

typedef __bf16 bf16x8 __attribute__((ext_vector_type(8)));
typedef float  f32x4  __attribute__((ext_vector_type(4)));

__device__ __forceinline__ unsigned short f2bf(float f) {
    unsigned u = __float_as_uint(f);
    unsigned r = u + 0x7fff + ((u >> 16) & 1);   // round-nearest-even to bf16
    return (unsigned short)(r >> 16);
}
__device__ __forceinline__ float bf2f(unsigned short h) {
    return __uint_as_float(((unsigned)h) << 16);
}

// stage-1 histogram: T[bucket][block] = #edges of this block's chunk in bucket
__global__ __launch_bounds__(256) void k_hist1(const int* __restrict__ dst,
                                               int* __restrict__ T, int E, int nbuck) {
    __shared__ int hist[NBMAX];
    for (int i = threadIdx.x; i < nbuck; i += 256) hist[i] = 0;
    __syncthreads();
    const int per = (E + NBC - 1) / NBC;
    const int beg = blockIdx.x * per, end = min(beg + per, E);
    for (int i = beg + threadIdx.x; i < end; i += 256)
        atomicAdd(&hist[dst[i] >> BSH], 1);
    __syncthreads();
    for (int b = threadIdx.x; b < nbuck; b += 256)
        T[b * NBC + blockIdx.x] = hist[b];
}

// hierarchical exclusive scan over m elements
__global__ __launch_bounds__(1024) void k_bsum(const int* __restrict__ in,
                                               int* __restrict__ bsum, int m) {
    __shared__ int red[16];
    const int t = threadIdx.x;
    const int i = blockIdx.x * 1024 + t;
    int v = (i < m) ? in[i] : 0;
#pragma unroll
    for (int o = 32; o; o >>= 1) v += __shfl_down(v, o);
    if ((t & 63) == 0) red[t >> 6] = v;
    __syncthreads();
    if (t == 0) {
        int s = 0;
#pragma unroll
        for (int w = 0; w < 16; ++w) s += red[w];
        bsum[blockIdx.x] = s;
    }
}

__global__ void k_sbsum(const int* __restrict__ bsum, int* __restrict__ boff, int nb) {
    if (threadIdx.x == 0 && blockIdx.x == 0) {
        int run = 0;
        for (int i = 0; i < nb; ++i) { boff[i] = run; run += bsum[i]; }
    }
}

__global__ __launch_bounds__(1024) void k_scanexc(
    const int* __restrict__ in, const int* __restrict__ boff,
    int* __restrict__ out, int m) {
    __shared__ int sh[1024];
    const int t = threadIdx.x;
    const int i = blockIdx.x * 1024 + t;
    const int v = (i < m) ? in[i] : 0;
    sh[t] = v;
    __syncthreads();
#pragma unroll
    for (int o = 1; o < 1024; o <<= 1) {
        int add = (t >= o) ? sh[t - o] : 0;
        __syncthreads();
        sh[t] += add;
        __syncthreads();
    }
    if (i < m) out[i] = boff[blockIdx.x] + sh[t] - v;
}

// stage-1 partition: block writes packed (d&127)<<17|src into its private
// contiguous run per bucket. Only LDS atomics; writes are L2-line-friendly.
__global__ __launch_bounds__(256) void k_part1(
    const int* __restrict__ src, const int* __restrict__ dst,
    const int* __restrict__ Toff, unsigned* __restrict__ stage, int E, int nbuck) {
    __shared__ int base[NBMAX];
    __shared__ int cnt[NBMAX];
    for (int i = threadIdx.x; i < nbuck; i += 256) {
        base[i] = Toff[i * NBC + blockIdx.x];
        cnt[i] = 0;
    }
    __syncthreads();
    const int per = (E + NBC - 1) / NBC;
    const int beg = blockIdx.x * per, end = min(beg + per, E);
    for (int i = beg + threadIdx.x; i < end; i += 256) {
        int d = dst[i], s = src[i];
        int b = d >> BSH;
        int p = atomicAdd(&cnt[b], 1);
        stage[base[b] + p] = ((unsigned)(d & 127) << 17) | (unsigned)s;
    }
}

// stage-2: one block per bucket. Fast path stages the whole bucket in LDS:
// one global read, count -> scan -> LDS permute -> coalesced csr writeback.
// Emits rowptr + dinv (degree for free). Global-path fallback if len > CAP.
__global__ __launch_bounds__(256) void k_part2(
    const int* __restrict__ Toff, const unsigned* __restrict__ stage,
    int* __restrict__ csr, int* __restrict__ rowptr, float* __restrict__ dinv,
    int n, int E, int nbuck) {
    __shared__ unsigned buf[CAP];
    __shared__ unsigned srt[CAP];
    __shared__ int cnt[128], sc[128], curs[128];
    __shared__ int rbs, res;
    const int t = threadIdx.x;
    const int b = blockIdx.x;
    if (t < 128) cnt[t] = 0;
    if (t == 0) {
        rbs = Toff[b * NBC];
        res = (b == nbuck - 1) ? E : Toff[(b + 1) * NBC];
    }
    __syncthreads();
    const int rb = rbs, re = res, len = re - rb;
    if (len <= CAP) {
        for (int i = t; i < len; i += 256) {
            unsigned r = stage[rb + i];
            buf[i] = r;
            atomicAdd(&cnt[(r >> 17) & 127], 1);
        }
        __syncthreads();
        if (t < 128) sc[t] = cnt[t];
        __syncthreads();
#pragma unroll
        for (int o = 1; o < 128; o <<= 1) {
            int add = (t < 128 && t >= o) ? sc[t - o] : 0;
            __syncthreads();
            if (t < 128) sc[t] += add;
            __syncthreads();
        }
        if (t < 128) {
            curs[t] = sc[t] - cnt[t];
            const int gi = b * 128 + t;
            if (gi < n) {
                rowptr[gi] = rb + sc[t] - cnt[t];
                dinv[gi] = rsqrtf((float)cnt[t] + 1.f);   // +1 = self-loop
                if (gi == n - 1) rowptr[n] = rb + sc[t];  // == E
            }
        }
        __syncthreads();
        for (int i = t; i < len; i += 256) {
            unsigned r = buf[i];
            int p = atomicAdd(&curs[(r >> 17) & 127], 1);
            srt[p] = r & 0x1FFFF;
        }
        __syncthreads();
        for (int i = t; i < len; i += 256) csr[rb + i] = (int)srt[i];
    } else {
        // fallback: two-pass over global stage, scatter to global csr
        for (int i = rb + t; i < re; i += 256)
            atomicAdd(&cnt[(stage[i] >> 17) & 127], 1);
        __syncthreads();
        if (t < 128) sc[t] = cnt[t];
        __syncthreads();
#pragma unroll
        for (int o = 1; o < 128; o <<= 1) {
            int add = (t < 128 && t >= o) ? sc[t - o] : 0;
            __syncthreads();
            if (t < 128) sc[t] += add;
            __syncthreads();
        }
        if (t < 128) {
            curs[t] = rb + sc[t] - cnt[t];
            const int gi = b * 128 + t;
            if (gi < n) {
                rowptr[gi] = rb + sc[t] - cnt[t];
                dinv[gi] = rsqrtf((float)cnt[t] + 1.f);
                if (gi == n - 1) rowptr[n] = rb + sc[t];
            }
        }
        __syncthreads();
        for (int i = rb + t; i < re; i += 256) {
            unsigned r = stage[i];
            int p = atomicAdd(&curs[(r >> 17) & 127], 1);
            csr[p] = (int)(r & 0x1FFFF);
        }
    }
}

// Pre-split W1[128][64] and W2[64][64] into MFMA-frag-ordered hi/lo bf16
// buffers, one launch.
__global__ void k_wsplit2(const float* __restrict__ W1, const float* __restrict__ W2,
                          unsigned short* __restrict__ W1s, unsigned short* __restrict__ W2s) {
    int i = blockIdx.x * blockDim.x + threadIdx.x;
    const float* W; unsigned short* out; int K, idx;
    if (i < 128 * 64)            { W = W1; out = W1s; K = 128; idx = i; }
    else if (i < 128 * 64 + 64 * 64) { W = W2; out = W2s; K = 64; idx = i - 128 * 64; }
    else return;
    int k = idx >> 6, c = idx & 63;
    float v = W[k * 64 + c];
    unsigned short hi = f2bf(v);
    unsigned short lo = f2bf(v - bf2f(hi));
    int T = K / 32;
    int t = k >> 5, kk = k & 31, g = kk >> 3, j = kk & 7;
    int ct = c >> 4, lane = g * 16 + (c & 15);
    out[(((size_t)(0 * T + t) * 4 + ct) * 64 + lane) * 8 + j] = hi;
    out[(((size_t)(1 * T + t) * 4 + ct) * 64 + lane) * 8 + j] = lo;
}

// hs[n x 64] = half((A[n x K] @ W[K x 64]) * dinv[row]) via bf16-split MFMA.
// One wave per 16 rows, no LDS, no barriers. A dtype = float or half.
template<int K, bool LEAKY, typename AT>
__global__ __launch_bounds__(256) void k_gemm_mfma(
    const AT* __restrict__ A, const unsigned short* __restrict__ Ws,
    const float* __restrict__ dinv, __half* __restrict__ C, int n) {
    constexpr int T = K / 32;
    const int lane = threadIdx.x & 63;
    const int w = blockIdx.x * 4 + (threadIdx.x >> 6);
    const int r0 = w * 16;
    if (r0 >= n) return;
    const int g = lane >> 4, rA = lane & 15;

    bf16x8 ahi[T], alo[T];
    const AT* arow = A + (size_t)(r0 + rA) * K + g * 8;
#pragma unroll
    for (int t = 0; t < T; ++t) {
        float f[8];
        if constexpr (std::is_same<AT, float>::value) {
            float4 v0 = *(const float4*)(arow + t * 32);
            float4 v1 = *(const float4*)(arow + t * 32 + 4);
            f[0] = v0.x; f[1] = v0.y; f[2] = v0.z; f[3] = v0.w;
            f[4] = v1.x; f[5] = v1.y; f[6] = v1.z; f[7] = v1.w;
        } else {
            union { uint4 q; __half h[8]; } u;
            u.q = *(const uint4*)(arow + t * 32);
#pragma unroll
            for (int j = 0; j < 8; ++j) f[j] = __half2float(u.h[j]);
        }
        union { unsigned short u[8]; bf16x8 v; } H, L;
#pragma unroll
        for (int j = 0; j < 8; ++j) {
            float x = f[j];
            if (LEAKY) x = x > 0.f ? x : 0.01f * x;
            unsigned short h = f2bf(x);
            H.u[j] = h;
            L.u[j] = f2bf(x - bf2f(h));
        }
        ahi[t] = H.v; alo[t] = L.v;
    }

    f32x4 acc[4];
#pragma unroll
    for (int ct = 0; ct < 4; ++ct) acc[ct] = (f32x4){0.f, 0.f, 0.f, 0.f};

#pragma unroll
    for (int ct = 0; ct < 4; ++ct) {
#pragma unroll
        for (int t = 0; t < T; ++t) {
            union { uint4 q; bf16x8 v; } Bh, Bl;
            Bh.q = *(const uint4*)(Ws + (((size_t)(0 * T + t) * 4 + ct) * 64 + lane) * 8);
            Bl.q = *(const uint4*)(Ws + (((size_t)(1 * T + t) * 4 + ct) * 64 + lane) * 8);
            acc[ct] = __builtin_amdgcn_mfma_f32_16x16x32_bf16(ahi[t], Bh.v, acc[ct], 0, 0, 0);
            acc[ct] = __builtin_amdgcn_mfma_f32_16x16x32_bf16(ahi[t], Bl.v, acc[ct], 0, 0, 0);
            acc[ct] = __builtin_amdgcn_mfma_f32_16x16x32_bf16(alo[t], Bh.v, acc[ct], 0, 0, 0);
        }
    }

    float dv[4];
#pragma unroll
    for (int r = 0; r < 4; ++r) dv[r] = dinv[r0 + g * 4 + r];

    __half* crow = C + (size_t)(r0 + g * 4) * 64 + rA;
#pragma unroll
    for (int ct = 0; ct < 4; ++ct)
#pragma unroll
        for (int r = 0; r < 4; ++r)
            crow[(size_t)r * 64 + ct * 16] = __float2half_rn(acc[ct][r] * dv[r]);
}

// out[d] = (sum_e hs[s_e] + hs[d]) * dinv[d] + bias   (OT = half or float)
// One wave per dst row; d wave-uniform -> csr loads are scalar (SMEM);
// 8-way unroll keeps 8 fp16 gathers (128B each) in flight.
template<typename OT>
__global__ __launch_bounds__(256) void k_aggcsr(
    const int* __restrict__ rowptr, const int* __restrict__ csr,
    const float* __restrict__ dinv, const __half* __restrict__ hs,
    const float* __restrict__ bias, OT* __restrict__ out, int n) {
    const int lane = threadIdx.x & 63;
    const int wid  = blockIdx.x * 4 + (threadIdx.x >> 6);
    const int nw   = gridDim.x * 4;
    const float bl = bias[lane];
    for (int dd = wid; dd < n; dd += nw) {
        const int d = __builtin_amdgcn_readfirstlane(dd);
        const int beg = rowptr[d], end = rowptr[d + 1];
        float a0 = 0.f, a1 = 0.f, a2 = 0.f, a3 = 0.f;
        float a4 = 0.f, a5 = 0.f, a6 = 0.f, a7 = 0.f;
        int j = beg;
        for (; j + 8 <= end; j += 8) {
            int s0 = csr[j + 0], s1 = csr[j + 1], s2 = csr[j + 2], s3 = csr[j + 3];
            int s4 = csr[j + 4], s5 = csr[j + 5], s6 = csr[j + 6], s7 = csr[j + 7];
            a0 += __half2float(hs[(size_t)s0 * 64 + lane]);
            a1 += __half2float(hs[(size_t)s1 * 64 + lane]);
            a2 += __half2float(hs[(size_t)s2 * 64 + lane]);
            a3 += __half2float(hs[(size_t)s3 * 64 + lane]);
            a4 += __half2float(hs[(size_t)s4 * 64 + lane]);
            a5 += __half2float(hs[(size_t)s5 * 64 + lane]);
            a6 += __half2float(hs[(size_t)s6 * 64 + lane]);
            a7 += __half2float(hs[(size_t)s7 * 64 + lane]);
        }
        for (; j < end; ++j)
            a0 += __half2float(hs[(size_t)csr[j] * 64 + lane]);
        const float di = dinv[d];
        const float acc = ((a0 + a1) + (a2 + a3)) + ((a4 + a5) + (a6 + a7));
        const float v = (acc + __half2float(hs[(size_t)d * 64 + lane])) * di + bl;
        if constexpr (std::is_same<OT, __half>::value)
            out[(size_t)d * 64 + lane] = __float2half_rn(v);
        else
            out[(size_t)d * 64 + lane] = v;
    }
}

extern "C" void kernel_launch(void* const* d_in, const int* in_sizes, int n_in,
                              void* d_out, int out_size, void* d_ws, size_t ws_size,
                              hipStream_t stream) {
    const float* x  = (const float*)d_in[0];
    const int*   ei = (const int*)d_in[1];
    const float* W1 = (const float*)d_in[2];
    const float* b1 = (const float*)d_in[3];
    const float* W2 = (const float*)d_in[4];
    const float* b2 = (const float*)d_in[5];
    float* out = (float*)d_out;

    const int n = in_sizes[0] / 128;   // 50000
    const int E = in_sizes[1] / 2;     // 800000
    const int* src = ei;
    const int* dst = ei + E;

    const int nbuck = (n + 127) >> BSH;        // 391
    const int m = nbuck * NBC;                 // 50048 table entries
    const int nb2 = (m + 1023) / 1024;         // 49 scan blocks

    char* ws = (char*)d_ws;
    size_t off = 0;
    auto alloc = [&](size_t bytes) { void* p = ws + off; off = (off + bytes + 255) & ~(size_t)255; return p; };
    int*      T      = (int*)alloc((size_t)m * 4);
    int*      Toff   = (int*)alloc((size_t)m * 4);
    int*      bsum   = (int*)alloc((size_t)nb2 * 4);
    int*      boff   = (int*)alloc((size_t)nb2 * 4);
    unsigned* stage  = (unsigned*)alloc((size_t)E * 4);
    int*      csr    = (int*)alloc((size_t)E * 4);
    int*      rowptr = (int*)alloc((size_t)(n + 1) * 4);
    float*    dinv   = (float*)alloc((size_t)n * 4);
    __half*   hs     = (__half*)alloc((size_t)n * 64 * 2);
    __half*   out1   = (__half*)alloc((size_t)n * 64 * 2);
    unsigned short* W1s = (unsigned short*)alloc((size_t)2 * 128 * 64 * 2);
    unsigned short* W2s = (unsigned short*)alloc((size_t)2 * 64 * 64 * 2);
    (void)ws_size; (void)n_in; (void)out_size;

    // CSR build: histogram -> scan -> 2-stage partition (no global atomics)
    k_hist1  <<<NBC, 256, 0, stream>>>(dst, T, E, nbuck);
    k_bsum   <<<nb2, 1024, 0, stream>>>(T, bsum, m);
    k_sbsum  <<<1, 64, 0, stream>>>(bsum, boff, nb2);
    k_scanexc<<<nb2, 1024, 0, stream>>>(T, boff, Toff, m);
    k_part1  <<<NBC, 256, 0, stream>>>(src, dst, Toff, stage, E, nbuck);
    k_part2  <<<nbuck, 256, 0, stream>>>(Toff, stage, csr, rowptr, dinv, n, E, nbuck);

    k_wsplit2<<<(128 * 64 + 64 * 64 + 255) / 256, 256, 0, stream>>>(W1, W2, W1s, W2s);

    const int gemmBlocks = (n / 16 + 3) / 4;   // one wave per 16 rows
    k_gemm_mfma<128, false, float><<<gemmBlocks, 256, 0, stream>>>(x, W1s, dinv, hs, n);
    k_aggcsr<__half><<<2048, 256, 0, stream>>>(rowptr, csr, dinv, hs, b1, out1, n);

    k_gemm_mfma<64, true, __half><<<gemmBlocks, 256, 0, stream>>>(out1, W2s, dinv, hs, n);
    k_aggcsr<float><<<2048, 256, 0, stream>>>(rowptr, csr, dinv, hs, b2, out, n);
}